// Round 1
// 9486.919 us; speedup vs baseline: 1.0420x; 1.0420x over previous
//
#include <hip/hip_runtime.h>
#include <hip/hip_bf16.h>
#include <math.h>

#define B_ 2
#define S_ 1024
#define E_ 768
#define H_ 12
#define D_ 64
#define I_ 3072
#define V_ 50257
#define RH_ 128
#define MAXD_ 4
#define L_ 4
#define NT (B_*S_)

__device__ __forceinline__ float waveSum(float v){
  #pragma unroll
  for (int o = 32; o > 0; o >>= 1) v += __shfl_xor(v, o);
  return v;
}
__device__ __forceinline__ float waveMax(float v){
  #pragma unroll
  for (int o = 32; o > 0; o >>= 1) v = fmaxf(v, __shfl_xor(v, o));
  return v;
}

// ---------------- embedding: h = tok_emb[ids] + pos_emb[s] ----------------
__global__ void embed_k(const int* __restrict__ ids, const float* __restrict__ tok,
                        const float* __restrict__ pos, float* __restrict__ h){
  int t = blockIdx.x;
  int s = t & (S_ - 1);
  long id = (long)ids[t];
  const float* tr = tok + id * (long)E_;
  const float* pr = pos + (long)s * E_;
  float* hr = h + (long)t * E_;
  for (int e = threadIdx.x; e < E_; e += blockDim.x)
    hr[e] = tr[e] + pr[e];
}

// ---------------- LayerNorm ----------------
__global__ __launch_bounds__(256) void ln_k(const float* __restrict__ x,
                                            const float* __restrict__ g,
                                            const float* __restrict__ b,
                                            float* __restrict__ y){
  int t = blockIdx.x;
  const float* xr = x + (long)t * E_;
  float* yr = y + (long)t * E_;
  float v[3];
  float s = 0.f, s2 = 0.f;
  #pragma unroll
  for (int i = 0; i < 3; i++){
    int e = threadIdx.x + i * 256;
    v[i] = xr[e];
    s += v[i]; s2 += v[i] * v[i];
  }
  __shared__ float rs[4], rq[4];
  float wsv = waveSum(s), wqv = waveSum(s2);
  int wid = threadIdx.x >> 6;
  if ((threadIdx.x & 63) == 0){ rs[wid] = wsv; rq[wid] = wqv; }
  __syncthreads();
  float S = rs[0] + rs[1] + rs[2] + rs[3];
  float Q = rq[0] + rq[1] + rq[2] + rq[3];
  float mu  = S * (1.0f / E_);
  float var = Q * (1.0f / E_) - mu * mu;
  float inv = 1.0f / sqrtf(var + 1e-5f);
  #pragma unroll
  for (int i = 0; i < 3; i++){
    int e = threadIdx.x + i * 256;
    yr[e] = (v[i] - mu) * inv * g[e] + b[e];
  }
}

// ---------------- router: relu(h@w1^T+b1)@w2^T+b2, argmax+1 ----------------
__global__ __launch_bounds__(128) void router_k(const float* __restrict__ h,
                                                const float* __restrict__ w1,
                                                const float* __restrict__ b1,
                                                const float* __restrict__ w2,
                                                const float* __restrict__ b2,
                                                int* __restrict__ dep,
                                                float* __restrict__ out_dep,
                                                float* __restrict__ out_rl){
  int t = blockIdx.x;
  int r = threadIdx.x;
  __shared__ float rh[RH_];
  __shared__ float lg[MAXD_];
  const float* hr = h + (long)t * E_;
  const float* wr = w1 + (long)r * E_;
  float acc = b1[r];
  for (int k = 0; k < E_; k += 4){
    float4 hv = *(const float4*)(hr + k);
    float4 wv = *(const float4*)(wr + k);
    acc = fmaf(hv.x, wv.x, acc); acc = fmaf(hv.y, wv.y, acc);
    acc = fmaf(hv.z, wv.z, acc); acc = fmaf(hv.w, wv.w, acc);
  }
  rh[r] = fmaxf(acc, 0.0f);
  __syncthreads();
  if (r < MAXD_){
    const float* w2r = w2 + r * RH_;
    float a = b2[r];
    for (int k = 0; k < RH_; k++) a = fmaf(rh[k], w2r[k], a);
    lg[r] = a;
    out_rl[t * MAXD_ + r] = a;
  }
  __syncthreads();
  if (r == 0){
    int best = 0; float bv = lg[0];
    #pragma unroll
    for (int d = 1; d < MAXD_; d++) if (lg[d] > bv){ bv = lg[d]; best = d; }  // first-max
    int dd = best + 1;  // MIN_DEPTH
    dep[t] = dd;
    out_dep[t] = (float)dd;
  }
}

// ---------------- GEMM: C[M,N] = A[M,K] @ B[N,K]^T + bias (+epilogue) ----------------
enum { EPI_NONE = 0, EPI_GELU = 1, EPI_RES = 2 };

template<int EPI>
__global__ __launch_bounds__(256) void gemm_bt(const float* __restrict__ A,
                                               const float* __restrict__ Bm,
                                               const float* __restrict__ bias,
                                               const float* __restrict__ R,
                                               float* __restrict__ C,
                                               int M, int N, int K){
  // [16][68]: 272B row stride keeps float4 alignment, breaks the 4-way
  // write conflict of stride-64 (lk*64+lr all landed in 16 banks).
  __shared__ float As[16][68];
  __shared__ float Bs[16][68];
  int tid = threadIdx.x;
  int tx = tid & 15, ty = tid >> 4;
  int m0 = blockIdx.y * 64, n0 = blockIdx.x * 64;
  int lr = tid >> 2;             // 0..63: tile row
  int lk = (tid & 3) << 2;       // 0,4,8,12: k offset
  float acc[4][4] = {};
  const float* Arow = A + (long)(m0 + lr) * K + lk;
  const float* Brow = Bm + (long)(n0 + lr) * K + lk;
  bool bvalid = (n0 + lr) < N;
  for (int kt = 0; kt < K; kt += 16){
    float4 av = *(const float4*)(Arow + kt);
    float4 bv = make_float4(0.f, 0.f, 0.f, 0.f);
    if (bvalid) bv = *(const float4*)(Brow + kt);
    __syncthreads();
    As[lk+0][lr] = av.x; As[lk+1][lr] = av.y; As[lk+2][lr] = av.z; As[lk+3][lr] = av.w;
    Bs[lk+0][lr] = bv.x; Bs[lk+1][lr] = bv.y; Bs[lk+2][lr] = bv.z; Bs[lk+3][lr] = bv.w;
    __syncthreads();
    #pragma unroll
    for (int kk = 0; kk < 16; kk++){
      float4 a4 = *(const float4*)&As[kk][ty << 2];
      float4 b4 = *(const float4*)&Bs[kk][tx << 2];
      float aa[4] = {a4.x, a4.y, a4.z, a4.w};
      float bb[4] = {b4.x, b4.y, b4.z, b4.w};
      #pragma unroll
      for (int i = 0; i < 4; i++)
        #pragma unroll
        for (int j = 0; j < 4; j++)
          acc[i][j] = fmaf(aa[i], bb[j], acc[i][j]);
    }
  }
  #pragma unroll
  for (int i = 0; i < 4; i++){
    int m = m0 + (ty << 2) + i;
    float* crow = C + (long)m * N;
    const float* rrow = (EPI == EPI_RES) ? (R + (long)m * N) : nullptr;
    #pragma unroll
    for (int j = 0; j < 4; j++){
      int n = n0 + (tx << 2) + j;
      if (n < N){
        float v = acc[i][j] + (bias ? bias[n] : 0.f);
        if (EPI == EPI_GELU) v = 0.5f * v * (1.0f + erff(v * 0.70710678118654752f));
        if (EPI == EPI_RES)  v += rrow[n];
        crow[n] = v;
      }
    }
  }
}

// ---------------- flash attention (additive 0/1 float mask, softmax over ALL keys) ----
// block = 32-query tile; K/V staged in LDS per 64-key tile (K/V L2 traffic /64 vs
// the old one-block-per-query kernel). Thread = (q = tid>>3, kg = tid&7), k = kg+8j.
// LDS stride 68 floats: rows 0..7 (one j-step) land on disjoint bank quads.
#define QT_ 32
#define KT_ 64
__global__ __launch_bounds__(256) void fattn_k(const float* __restrict__ qkv,
                                               const int* __restrict__ dep,
                                               float* __restrict__ out, int depth){
  int qt = blockIdx.x, hd = blockIdx.y, b = blockIdx.z;
  int tid = threadIdx.x;
  int q  = tid >> 3;     // 0..31
  int kg = tid & 7;      // 0..7
  int qglob = qt * QT_ + q;
  long trow = (long)(b * S_ + qglob);
  const float* qrow = qkv + trow * 2304 + hd * 64;

  __shared__ float Ks[KT_][68];
  __shared__ float Vs[KT_][68];
  __shared__ float bk[KT_];

  // Q row in registers (64 floats)
  float4 Qr[16];
  #pragma unroll
  for (int i = 0; i < 16; i++) Qr[i] = *(const float4*)(qrow + i * 4);

  bool dq = dep[b * S_ + qglob] >= depth;

  float m = -1e30f, l = 0.f;
  float O[64];
  #pragma unroll
  for (int d = 0; d < 64; d++) O[d] = 0.f;

  int srow = tid >> 2;              // 0..63 staging row
  int sseg = (tid & 3) << 4;        // 0,16,32,48

  for (int kt = 0; kt < S_; kt += KT_){
    __syncthreads();   // previous tile fully consumed
    {
      const float* kr = qkv + (long)(b * S_ + kt + srow) * 2304 + 768 + hd * 64 + sseg;
      const float* vr = kr + 768;
      float4 k0 = *(const float4*)(kr + 0);
      float4 k1 = *(const float4*)(kr + 4);
      float4 k2 = *(const float4*)(kr + 8);
      float4 k3 = *(const float4*)(kr + 12);
      float4 v0 = *(const float4*)(vr + 0);
      float4 v1 = *(const float4*)(vr + 4);
      float4 v2 = *(const float4*)(vr + 8);
      float4 v3 = *(const float4*)(vr + 12);
      *(float4*)&Ks[srow][sseg + 0]  = k0;
      *(float4*)&Ks[srow][sseg + 4]  = k1;
      *(float4*)&Ks[srow][sseg + 8]  = k2;
      *(float4*)&Ks[srow][sseg + 12] = k3;
      *(float4*)&Vs[srow][sseg + 0]  = v0;
      *(float4*)&Vs[srow][sseg + 4]  = v1;
      *(float4*)&Vs[srow][sseg + 8]  = v2;
      *(float4*)&Vs[srow][sseg + 12] = v3;
      if (tid < KT_) bk[tid] = (dep[b * S_ + kt + tid] >= depth) ? 1.0f : 0.0f;
    }
    __syncthreads();

    // scores for this thread's 8 keys
    float s[8];
    #pragma unroll
    for (int j = 0; j < 8; j++){
      int kk = kg + (j << 3);
      const float* krow = &Ks[kk][0];
      float dot = 0.f;
      #pragma unroll
      for (int d4 = 0; d4 < 16; d4++){
        float4 kv = *(const float4*)(krow + (d4 << 2));
        dot = fmaf(Qr[d4].x, kv.x, dot);
        dot = fmaf(Qr[d4].y, kv.y, dot);
        dot = fmaf(Qr[d4].z, kv.z, dot);
        dot = fmaf(Qr[d4].w, kv.w, dot);
      }
      int kglob = kt + kk;
      float boost = (dq && kglob <= qglob) ? bk[kk] : 0.0f;
      s[j] = dot * 0.125f + boost;
    }

    // online softmax update
    float tm = m;
    #pragma unroll
    for (int j = 0; j < 8; j++) tm = fmaxf(tm, s[j]);
    float scale = expf(m - tm);
    l *= scale;
    #pragma unroll
    for (int d = 0; d < 64; d++) O[d] *= scale;
    float p[8];
    #pragma unroll
    for (int j = 0; j < 8; j++){ p[j] = expf(s[j] - tm); l += p[j]; }
    m = tm;

    // PV accumulate
    #pragma unroll
    for (int j = 0; j < 8; j++){
      int kk = kg + (j << 3);
      const float* vrow = &Vs[kk][0];
      #pragma unroll
      for (int d4 = 0; d4 < 16; d4++){
        float4 vv = *(const float4*)(vrow + (d4 << 2));
        O[(d4 << 2) + 0] = fmaf(p[j], vv.x, O[(d4 << 2) + 0]);
        O[(d4 << 2) + 1] = fmaf(p[j], vv.y, O[(d4 << 2) + 1]);
        O[(d4 << 2) + 2] = fmaf(p[j], vv.z, O[(d4 << 2) + 2]);
        O[(d4 << 2) + 3] = fmaf(p[j], vv.w, O[(d4 << 2) + 3]);
      }
    }
  }

  // merge the 8 kg-partials (same wave: kg = tid&7)
  #pragma unroll
  for (int o = 1; o <= 4; o <<= 1){
    float m2 = __shfl_xor(m, o);
    float l2 = __shfl_xor(l, o);
    float mn = fmaxf(m, m2);
    float ea = expf(m - mn), eb = expf(m2 - mn);
    l = l * ea + l2 * eb;
    #pragma unroll
    for (int d = 0; d < 64; d++)
      O[d] = O[d] * ea + __shfl_xor(O[d], o) * eb;
    m = mn;
  }
  if (kg == 0){
    float inv = 1.0f / l;
    float* orow = out + trow * 768 + hd * 64;
    #pragma unroll
    for (int d4 = 0; d4 < 16; d4++){
      float4 ov = make_float4(O[(d4 << 2) + 0] * inv, O[(d4 << 2) + 1] * inv,
                              O[(d4 << 2) + 2] * inv, O[(d4 << 2) + 3] * inv);
      *(float4*)(orow + (d4 << 2)) = ov;
    }
  }
}

// ---------------- router aux loss ----------------
__global__ __launch_bounds__(256) void loss_k(const float* __restrict__ rl,
                                              const int* __restrict__ dep,
                                              float* __restrict__ out){
  float p[4] = {0, 0, 0, 0};
  float ds = 0.f;
  for (int t = threadIdx.x; t < NT; t += 256){
    float l0 = rl[t*4+0], l1 = rl[t*4+1], l2 = rl[t*4+2], l3 = rl[t*4+3];
    float m = fmaxf(fmaxf(l0, l1), fmaxf(l2, l3));
    float e0 = expf(l0 - m), e1 = expf(l1 - m), e2 = expf(l2 - m), e3 = expf(l3 - m);
    float inv = 1.0f / (e0 + e1 + e2 + e3);
    p[0] += e0 * inv; p[1] += e1 * inv; p[2] += e2 * inv; p[3] += e3 * inv;
    ds += (float)dep[t];
  }
  __shared__ float red[4][5];
  float a0 = waveSum(p[0]), a1 = waveSum(p[1]), a2 = waveSum(p[2]), a3 = waveSum(p[3]);
  float a4 = waveSum(ds);
  int wid = threadIdx.x >> 6;
  if ((threadIdx.x & 63) == 0){
    red[wid][0] = a0; red[wid][1] = a1; red[wid][2] = a2; red[wid][3] = a3; red[wid][4] = a4;
  }
  __syncthreads();
  if (threadIdx.x == 0){
    float mp[4];
    for (int d = 0; d < 4; d++) mp[d] = red[0][d] + red[1][d] + red[2][d] + red[3][d];
    float dsum = red[0][4] + red[1][4] + red[2][4] + red[3][4];
    const float u = 0.25f;
    float lb = 0.f;
    for (int d = 0; d < 4; d++){
      float mean = mp[d] / (float)NT;
      lb += u * (logf(u) - logf(mean));
    }
    lb *= 0.25f;                                   // / MAXD
    float sparsity = dsum / (float)NT * 0.25f;     // mean(depths)/MAXD
    out[0] = 0.01f * lb + 0.001f * sparsity;
  }
}

extern "C" void kernel_launch(void* const* d_in, const int* in_sizes, int n_in,
                              void* d_out, int out_size, void* d_ws, size_t ws_size,
                              hipStream_t stream){
  const int*   ids  = (const int*)d_in[0];
  const float* tok  = (const float*)d_in[1];
  const float* pos  = (const float*)d_in[2];
  const float* rw1  = (const float*)d_in[3];
  const float* rb1  = (const float*)d_in[4];
  const float* rw2  = (const float*)d_in[5];
  const float* rb2  = (const float*)d_in[6];
  const float* wqkv = (const float*)d_in[7];
  const float* bqkv = (const float*)d_in[8];
  const float* wo   = (const float*)d_in[9];
  const float* bo   = (const float*)d_in[10];
  const float* ln1g = (const float*)d_in[11];
  const float* ln1b = (const float*)d_in[12];
  const float* ln2g = (const float*)d_in[13];
  const float* ln2b = (const float*)d_in[14];
  const float* w1   = (const float*)d_in[15];
  const float* b1   = (const float*)d_in[16];
  const float* w2   = (const float*)d_in[17];
  const float* b2   = (const float*)d_in[18];
  const float* lnfg = (const float*)d_in[19];
  const float* lnfb = (const float*)d_in[20];
  const float* lmh  = (const float*)d_in[21];

  // workspace layout (~44 MB)
  float* ws   = (float*)d_ws;
  float* h    = ws;                       // [2048,768]
  float* lnb  = h   + (long)NT * E_;      // [2048,768]
  float* big  = lnb + (long)NT * E_;      // [2048,3072] (qkv uses [2048,2304])
  float* attn = big + (long)NT * I_;      // [2048,768]
  int*   dep  = (int*)(attn + (long)NT * E_); // [2048]

  // output layout: logits | depths | loss | router_logits
  float* out        = (float*)d_out;
  float* out_logits = out;
  float* out_dep    = out + (long)NT * V_;
  float* out_loss   = out_dep + NT;
  float* out_rl     = out_loss + 1;

  embed_k<<<NT, 256, 0, stream>>>(ids, tok, pos, h);
  router_k<<<NT, 128, 0, stream>>>(h, rw1, rb1, rw2, rb2, dep, out_dep, out_rl);

  for (int depth = 1; depth <= MAXD_; ++depth){
    int li = depth - 1;   // (depth-1) % L with L==MAXD
    ln_k<<<NT, 256, 0, stream>>>(h, ln1g + li * E_, ln1b + li * E_, lnb);
    gemm_bt<EPI_NONE><<<dim3(36, 32), 256, 0, stream>>>(
        lnb, wqkv + (long)li * 3 * E_ * E_, bqkv + li * 3 * E_, nullptr, big, NT, 3 * E_, E_);
    fattn_k<<<dim3(S_ / QT_, H_, B_), 256, 0, stream>>>(big, dep, attn, depth);
    gemm_bt<EPI_RES><<<dim3(12, 32), 256, 0, stream>>>(
        attn, wo + (long)li * E_ * E_, bo + li * E_, h, h, NT, E_, E_);
    ln_k<<<NT, 256, 0, stream>>>(h, ln2g + li * E_, ln2b + li * E_, lnb);
    gemm_bt<EPI_GELU><<<dim3(48, 32), 256, 0, stream>>>(
        lnb, w1 + (long)li * I_ * E_, b1 + li * I_, nullptr, big, NT, I_, E_);
    gemm_bt<EPI_RES><<<dim3(12, 32), 256, 0, stream>>>(
        big, w2 + (long)li * E_ * I_, b2 + li * E_, h, h, NT, E_, I_);
  }

  ln_k<<<NT, 256, 0, stream>>>(h, lnfg, lnfb, lnb);
  gemm_bt<EPI_NONE><<<dim3((V_ + 63) / 64, 32), 256, 0, stream>>>(
      lnb, lmh, nullptr, nullptr, out_logits, NT, V_, E_);
  loss_k<<<1, 256, 0, stream>>>(out_rl, dep, out_loss);
}

// Round 3
// 7036.616 us; speedup vs baseline: 1.4049x; 1.3482x over previous
//
#include <hip/hip_runtime.h>
#include <hip/hip_bf16.h>
#include <math.h>

#define B_ 2
#define S_ 1024
#define E_ 768
#define H_ 12
#define D_ 64
#define I_ 3072
#define V_ 50257
#define RH_ 128
#define MAXD_ 4
#define L_ 4
#define NT (B_*S_)

typedef __attribute__((ext_vector_type(8))) short  s8v;   // 8 bf16 (4 VGPRs) MFMA frag
typedef __attribute__((ext_vector_type(4))) float  f4v;   // 4 fp32 MFMA acc
typedef __attribute__((ext_vector_type(4))) unsigned short us4;

__device__ __forceinline__ float waveSum(float v){
  #pragma unroll
  for (int o = 32; o > 0; o >>= 1) v += __shfl_xor(v, o);
  return v;
}
__device__ __forceinline__ float waveMax(float v){
  #pragma unroll
  for (int o = 32; o > 0; o >>= 1) v = fmaxf(v, __shfl_xor(v, o));
  return v;
}

// split fp32 into bf16 hi (trunc) + bf16 lo (RNE of residual); x ~= hi + lo to ~2^-16 rel
__device__ __forceinline__ void bsplit(float x, unsigned short& h, unsigned short& l){
  unsigned u = __float_as_uint(x);
  h = (unsigned short)(u >> 16);
  float hf = __uint_as_float(u & 0xFFFF0000u);
  unsigned v = __float_as_uint(x - hf);
  unsigned r = v + 0x7FFFu + ((v >> 16) & 1u);
  l = (unsigned short)(r >> 16);
}

// ---------------- embedding: h = tok_emb[ids] + pos_emb[s] ----------------
__global__ void embed_k(const int* __restrict__ ids, const float* __restrict__ tok,
                        const float* __restrict__ pos, float* __restrict__ h){
  int t = blockIdx.x;
  int s = t & (S_ - 1);
  long id = (long)ids[t];
  const float* tr = tok + id * (long)E_;
  const float* pr = pos + (long)s * E_;
  float* hr = h + (long)t * E_;
  for (int e = threadIdx.x; e < E_; e += blockDim.x)
    hr[e] = tr[e] + pr[e];
}

// ---------------- LayerNorm ----------------
__global__ __launch_bounds__(256) void ln_k(const float* __restrict__ x,
                                            const float* __restrict__ g,
                                            const float* __restrict__ b,
                                            float* __restrict__ y){
  int t = blockIdx.x;
  const float* xr = x + (long)t * E_;
  float* yr = y + (long)t * E_;
  float v[3];
  float s = 0.f, s2 = 0.f;
  #pragma unroll
  for (int i = 0; i < 3; i++){
    int e = threadIdx.x + i * 256;
    v[i] = xr[e];
    s += v[i]; s2 += v[i] * v[i];
  }
  __shared__ float rs[4], rq[4];
  float wsv = waveSum(s), wqv = waveSum(s2);
  int wid = threadIdx.x >> 6;
  if ((threadIdx.x & 63) == 0){ rs[wid] = wsv; rq[wid] = wqv; }
  __syncthreads();
  float S = rs[0] + rs[1] + rs[2] + rs[3];
  float Q = rq[0] + rq[1] + rq[2] + rq[3];
  float mu  = S * (1.0f / E_);
  float var = Q * (1.0f / E_) - mu * mu;
  float inv = 1.0f / sqrtf(var + 1e-5f);
  #pragma unroll
  for (int i = 0; i < 3; i++){
    int e = threadIdx.x + i * 256;
    yr[e] = (v[i] - mu) * inv * g[e] + b[e];
  }
}

// ---------------- router: relu(h@w1^T+b1)@w2^T+b2, argmax+1 ----------------
__global__ __launch_bounds__(128) void router_k(const float* __restrict__ h,
                                                const float* __restrict__ w1,
                                                const float* __restrict__ b1,
                                                const float* __restrict__ w2,
                                                const float* __restrict__ b2,
                                                int* __restrict__ dep,
                                                float* __restrict__ out_dep,
                                                float* __restrict__ out_rl){
  int t = blockIdx.x;
  int r = threadIdx.x;
  __shared__ float rh[RH_];
  __shared__ float lg[MAXD_];
  const float* hr = h + (long)t * E_;
  const float* wr = w1 + (long)r * E_;
  float acc = b1[r];
  for (int k = 0; k < E_; k += 4){
    float4 hv = *(const float4*)(hr + k);
    float4 wv = *(const float4*)(wr + k);
    acc = fmaf(hv.x, wv.x, acc); acc = fmaf(hv.y, wv.y, acc);
    acc = fmaf(hv.z, wv.z, acc); acc = fmaf(hv.w, wv.w, acc);
  }
  rh[r] = fmaxf(acc, 0.0f);
  __syncthreads();
  if (r < MAXD_){
    const float* w2r = w2 + r * RH_;
    float a = b2[r];
    for (int k = 0; k < RH_; k++) a = fmaf(rh[k], w2r[k], a);
    lg[r] = a;
    out_rl[t * MAXD_ + r] = a;
  }
  __syncthreads();
  if (r == 0){
    int best = 0; float bv = lg[0];
    #pragma unroll
    for (int d = 1; d < MAXD_; d++) if (lg[d] > bv){ bv = lg[d]; best = d; }  // first-max
    int dd = best + 1;  // MIN_DEPTH
    dep[t] = dd;
    out_dep[t] = (float)dd;
  }
}

// ---------------- MFMA GEMM (bf16x3 split): C[M,N] = A[M,K] @ B[N,K]^T + bias ----------
// 128x128 block tile, BK=32, 4 waves each 64x64 (4x4 frags of 16x16x32).
// fp32 -> (hi,lo) bf16 split staged via registers into LDS (row stride 40 ushorts = 80B:
// frag ds_read_b128 hits 8 distinct bank-quads per 16-lane group -> 2-way, free).
// Accuracy: Ah*Bh + Ah*Bl + Al*Bh in fp32 acc; dropped Al*Bl ~ 1.5e-5 rel.
enum { EPI_NONE = 0, EPI_GELU = 1, EPI_RES = 2 };

template<int EPI>
__global__ __launch_bounds__(256) void mgemm(const float* __restrict__ A,
                                             const float* __restrict__ Bm,
                                             const float* __restrict__ bias,
                                             const float* __restrict__ R,
                                             float* __restrict__ C,
                                             int M, int N, int K){
  __shared__ alignas(16) unsigned short Ah[128][40], Al[128][40];
  __shared__ alignas(16) unsigned short Bh[128][40], Bl[128][40];
  int tid  = threadIdx.x;
  int lane = tid & 63;
  int wid  = tid >> 6;
  int wm = wid >> 1, wn = wid & 1;       // 2x2 wave grid, 64x64 each
  int fr = lane & 15, kg = lane >> 4;    // frag row / k-group
  int m0 = blockIdx.y << 7, n0 = blockIdx.x << 7;

  // staging: thread -> (row = tid>>1, k-half = (tid&1)*16); 16 floats each for A and B
  int srow = tid >> 1;
  int sk   = (tid & 1) << 4;
  const float* Ag = A + (long)(m0 + srow) * K + sk;
  int brow = n0 + srow;
  bool bval = brow < N;
  const float* Bg = Bm + (long)(bval ? brow : 0) * K + sk;

  f4v acc[4][4];
  #pragma unroll
  for (int i = 0; i < 4; i++)
    #pragma unroll
    for (int j = 0; j < 4; j++)
      acc[i][j] = (f4v){0.f, 0.f, 0.f, 0.f};

  for (int kt = 0; kt < K; kt += 32){
    float4 a4[4], b4[4];
    #pragma unroll
    for (int q = 0; q < 4; q++){
      a4[q] = *(const float4*)(Ag + kt + (q << 2));
      b4[q] = bval ? *(const float4*)(Bg + kt + (q << 2)) : make_float4(0.f, 0.f, 0.f, 0.f);
    }
    __syncthreads();   // previous tile consumed
    #pragma unroll
    for (int q = 0; q < 4; q++){
      us4 hA, lA, hB, lB;
      float av[4] = {a4[q].x, a4[q].y, a4[q].z, a4[q].w};
      float bv_[4] = {b4[q].x, b4[q].y, b4[q].z, b4[q].w};
      #pragma unroll
      for (int e = 0; e < 4; e++){
        unsigned short h_, l_;
        bsplit(av[e], h_, l_);  hA[e] = h_; lA[e] = l_;
        bsplit(bv_[e], h_, l_); hB[e] = h_; lB[e] = l_;
      }
      *(us4*)&Ah[srow][sk + (q << 2)] = hA;
      *(us4*)&Al[srow][sk + (q << 2)] = lA;
      *(us4*)&Bh[srow][sk + (q << 2)] = hB;
      *(us4*)&Bl[srow][sk + (q << 2)] = lB;
    }
    __syncthreads();

    s8v fah[4], fal[4], fbh[4], fbl[4];
    #pragma unroll
    for (int i = 0; i < 4; i++){
      int ar = (wm << 6) + (i << 4) + fr;
      int br = (wn << 6) + (i << 4) + fr;
      fah[i] = *(const s8v*)&Ah[ar][kg << 3];
      fal[i] = *(const s8v*)&Al[ar][kg << 3];
      fbh[i] = *(const s8v*)&Bh[br][kg << 3];
      fbl[i] = *(const s8v*)&Bl[br][kg << 3];
    }
    #pragma unroll
    for (int i = 0; i < 4; i++)
      #pragma unroll
      for (int j = 0; j < 4; j++){
        acc[i][j] = __builtin_amdgcn_mfma_f32_16x16x32_bf16(fah[i], fbh[j], acc[i][j], 0, 0, 0);
        acc[i][j] = __builtin_amdgcn_mfma_f32_16x16x32_bf16(fah[i], fbl[j], acc[i][j], 0, 0, 0);
        acc[i][j] = __builtin_amdgcn_mfma_f32_16x16x32_bf16(fal[i], fbh[j], acc[i][j], 0, 0, 0);
      }
  }

  // epilogue: C/D layout col = lane&15, row = (lane>>4)*4 + reg
  #pragma unroll
  for (int j = 0; j < 4; j++){
    int c = n0 + (wn << 6) + (j << 4) + fr;
    if (c < N){
      float bv_ = bias ? bias[c] : 0.f;
      #pragma unroll
      for (int i = 0; i < 4; i++){
        int rbase = m0 + (wm << 6) + (i << 4) + (kg << 2);
        #pragma unroll
        for (int r = 0; r < 4; r++){
          long off = (long)(rbase + r) * N + c;
          float v = acc[i][j][r] + bv_;
          if (EPI == EPI_GELU) v = 0.5f * v * (1.0f + erff(v * 0.70710678118654752f));
          if (EPI == EPI_RES)  v += R[off];
          C[off] = v;
        }
      }
    }
  }
}

// ---------------- flash attention (additive 0/1 float mask, softmax over ALL keys) ----
#define QT_ 32
#define KT_ 64
__global__ __launch_bounds__(256) void fattn_k(const float* __restrict__ qkv,
                                               const int* __restrict__ dep,
                                               float* __restrict__ out, int depth){
  int qt = blockIdx.x, hd = blockIdx.y, b = blockIdx.z;
  int tid = threadIdx.x;
  int q  = tid >> 3;     // 0..31
  int kg = tid & 7;      // 0..7
  int qglob = qt * QT_ + q;
  long trow = (long)(b * S_ + qglob);
  const float* qrow = qkv + trow * 2304 + hd * 64;

  __shared__ alignas(16) float Ks[KT_][68];
  __shared__ alignas(16) float Vs[KT_][68];
  __shared__ float bk[KT_];

  float4 Qr[16];
  #pragma unroll
  for (int i = 0; i < 16; i++) Qr[i] = *(const float4*)(qrow + i * 4);

  bool dq = dep[b * S_ + qglob] >= depth;

  float m = -1e30f, l = 0.f;
  float O[64];
  #pragma unroll
  for (int d = 0; d < 64; d++) O[d] = 0.f;

  int srow = tid >> 2;
  int sseg = (tid & 3) << 4;

  for (int kt = 0; kt < S_; kt += KT_){
    __syncthreads();
    {
      const float* kr = qkv + (long)(b * S_ + kt + srow) * 2304 + 768 + hd * 64 + sseg;
      const float* vr = kr + 768;
      float4 k0 = *(const float4*)(kr + 0);
      float4 k1 = *(const float4*)(kr + 4);
      float4 k2 = *(const float4*)(kr + 8);
      float4 k3 = *(const float4*)(kr + 12);
      float4 v0 = *(const float4*)(vr + 0);
      float4 v1 = *(const float4*)(vr + 4);
      float4 v2 = *(const float4*)(vr + 8);
      float4 v3 = *(const float4*)(vr + 12);
      *(float4*)&Ks[srow][sseg + 0]  = k0;
      *(float4*)&Ks[srow][sseg + 4]  = k1;
      *(float4*)&Ks[srow][sseg + 8]  = k2;
      *(float4*)&Ks[srow][sseg + 12] = k3;
      *(float4*)&Vs[srow][sseg + 0]  = v0;
      *(float4*)&Vs[srow][sseg + 4]  = v1;
      *(float4*)&Vs[srow][sseg + 8]  = v2;
      *(float4*)&Vs[srow][sseg + 12] = v3;
      if (tid < KT_) bk[tid] = (dep[b * S_ + kt + tid] >= depth) ? 1.0f : 0.0f;
    }
    __syncthreads();

    float s[8];
    #pragma unroll
    for (int j = 0; j < 8; j++){
      int kk = kg + (j << 3);
      const float* krow = &Ks[kk][0];
      float dot = 0.f;
      #pragma unroll
      for (int d4 = 0; d4 < 16; d4++){
        float4 kv = *(const float4*)(krow + (d4 << 2));
        dot = fmaf(Qr[d4].x, kv.x, dot);
        dot = fmaf(Qr[d4].y, kv.y, dot);
        dot = fmaf(Qr[d4].z, kv.z, dot);
        dot = fmaf(Qr[d4].w, kv.w, dot);
      }
      int kglob = kt + kk;
      float boost = (dq && kglob <= qglob) ? bk[kk] : 0.0f;
      s[j] = dot * 0.125f + boost;
    }

    float tm = m;
    #pragma unroll
    for (int j = 0; j < 8; j++) tm = fmaxf(tm, s[j]);
    float scale = expf(m - tm);
    l *= scale;
    #pragma unroll
    for (int d = 0; d < 64; d++) O[d] *= scale;
    float p[8];
    #pragma unroll
    for (int j = 0; j < 8; j++){ p[j] = expf(s[j] - tm); l += p[j]; }
    m = tm;

    #pragma unroll
    for (int j = 0; j < 8; j++){
      int kk = kg + (j << 3);
      const float* vrow = &Vs[kk][0];
      #pragma unroll
      for (int d4 = 0; d4 < 16; d4++){
        float4 vv = *(const float4*)(vrow + (d4 << 2));
        O[(d4 << 2) + 0] = fmaf(p[j], vv.x, O[(d4 << 2) + 0]);
        O[(d4 << 2) + 1] = fmaf(p[j], vv.y, O[(d4 << 2) + 1]);
        O[(d4 << 2) + 2] = fmaf(p[j], vv.z, O[(d4 << 2) + 2]);
        O[(d4 << 2) + 3] = fmaf(p[j], vv.w, O[(d4 << 2) + 3]);
      }
    }
  }

  #pragma unroll
  for (int o = 1; o <= 4; o <<= 1){
    float m2 = __shfl_xor(m, o);
    float l2 = __shfl_xor(l, o);
    float mn = fmaxf(m, m2);
    float ea = expf(m - mn), eb = expf(m2 - mn);
    l = l * ea + l2 * eb;
    #pragma unroll
    for (int d = 0; d < 64; d++)
      O[d] = O[d] * ea + __shfl_xor(O[d], o) * eb;
    m = mn;
  }
  if (kg == 0){
    float inv = 1.0f / l;
    float* orow = out + trow * 768 + hd * 64;
    #pragma unroll
    for (int d4 = 0; d4 < 16; d4++){
      float4 ov = make_float4(O[(d4 << 2) + 0] * inv, O[(d4 << 2) + 1] * inv,
                              O[(d4 << 2) + 2] * inv, O[(d4 << 2) + 3] * inv);
      *(float4*)(orow + (d4 << 2)) = ov;
    }
  }
}

// ---------------- router aux loss ----------------
__global__ __launch_bounds__(256) void loss_k(const float* __restrict__ rl,
                                              const int* __restrict__ dep,
                                              float* __restrict__ out){
  float p[4] = {0, 0, 0, 0};
  float ds = 0.f;
  for (int t = threadIdx.x; t < NT; t += 256){
    float l0 = rl[t*4+0], l1 = rl[t*4+1], l2 = rl[t*4+2], l3 = rl[t*4+3];
    float m = fmaxf(fmaxf(l0, l1), fmaxf(l2, l3));
    float e0 = expf(l0 - m), e1 = expf(l1 - m), e2 = expf(l2 - m), e3 = expf(l3 - m);
    float inv = 1.0f / (e0 + e1 + e2 + e3);
    p[0] += e0 * inv; p[1] += e1 * inv; p[2] += e2 * inv; p[3] += e3 * inv;
    ds += (float)dep[t];
  }
  __shared__ float red[4][5];
  float a0 = waveSum(p[0]), a1 = waveSum(p[1]), a2 = waveSum(p[2]), a3 = waveSum(p[3]);
  float a4 = waveSum(ds);
  int wid = threadIdx.x >> 6;
  if ((threadIdx.x & 63) == 0){
    red[wid][0] = a0; red[wid][1] = a1; red[wid][2] = a2; red[wid][3] = a3; red[wid][4] = a4;
  }
  __syncthreads();
  if (threadIdx.x == 0){
    float mp[4];
    for (int d = 0; d < 4; d++) mp[d] = red[0][d] + red[1][d] + red[2][d] + red[3][d];
    float dsum = red[0][4] + red[1][4] + red[2][4] + red[3][4];
    const float u = 0.25f;
    float lb = 0.f;
    for (int d = 0; d < 4; d++){
      float mean = mp[d] / (float)NT;
      lb += u * (logf(u) - logf(mean));
    }
    lb *= 0.25f;
    float sparsity = dsum / (float)NT * 0.25f;
    out[0] = 0.01f * lb + 0.001f * sparsity;
  }
}

extern "C" void kernel_launch(void* const* d_in, const int* in_sizes, int n_in,
                              void* d_out, int out_size, void* d_ws, size_t ws_size,
                              hipStream_t stream){
  const int*   ids  = (const int*)d_in[0];
  const float* tok  = (const float*)d_in[1];
  const float* pos  = (const float*)d_in[2];
  const float* rw1  = (const float*)d_in[3];
  const float* rb1  = (const float*)d_in[4];
  const float* rw2  = (const float*)d_in[5];
  const float* rb2  = (const float*)d_in[6];
  const float* wqkv = (const float*)d_in[7];
  const float* bqkv = (const float*)d_in[8];
  const float* wo   = (const float*)d_in[9];
  const float* bo   = (const float*)d_in[10];
  const float* ln1g = (const float*)d_in[11];
  const float* ln1b = (const float*)d_in[12];
  const float* ln2g = (const float*)d_in[13];
  const float* ln2b = (const float*)d_in[14];
  const float* w1   = (const float*)d_in[15];
  const float* b1   = (const float*)d_in[16];
  const float* w2   = (const float*)d_in[17];
  const float* b2   = (const float*)d_in[18];
  const float* lnfg = (const float*)d_in[19];
  const float* lnfb = (const float*)d_in[20];
  const float* lmh  = (const float*)d_in[21];

  // workspace layout (~44 MB)
  float* ws   = (float*)d_ws;
  float* h    = ws;                       // [2048,768]
  float* lnb  = h   + (long)NT * E_;      // [2048,768]
  float* big  = lnb + (long)NT * E_;      // [2048,3072] (qkv uses [2048,2304])
  float* attn = big + (long)NT * I_;      // [2048,768]
  int*   dep  = (int*)(attn + (long)NT * E_); // [2048]

  // output layout: logits | depths | loss | router_logits
  float* out        = (float*)d_out;
  float* out_logits = out;
  float* out_dep    = out + (long)NT * V_;
  float* out_loss   = out_dep + NT;
  float* out_rl     = out_loss + 1;

  embed_k<<<NT, 256, 0, stream>>>(ids, tok, pos, h);
  router_k<<<NT, 128, 0, stream>>>(h, rw1, rb1, rw2, rb2, dep, out_dep, out_rl);

  for (int depth = 1; depth <= MAXD_; ++depth){
    int li = depth - 1;   // (depth-1) % L with L==MAXD
    ln_k<<<NT, 256, 0, stream>>>(h, ln1g + li * E_, ln1b + li * E_, lnb);
    mgemm<EPI_NONE><<<dim3(18, 16), 256, 0, stream>>>(
        lnb, wqkv + (long)li * 3 * E_ * E_, bqkv + li * 3 * E_, nullptr, big, NT, 3 * E_, E_);
    fattn_k<<<dim3(S_ / QT_, H_, B_), 256, 0, stream>>>(big, dep, attn, depth);
    mgemm<EPI_RES><<<dim3(6, 16), 256, 0, stream>>>(
        attn, wo + (long)li * E_ * E_, bo + li * E_, h, h, NT, E_, E_);
    ln_k<<<NT, 256, 0, stream>>>(h, ln2g + li * E_, ln2b + li * E_, lnb);
    mgemm<EPI_GELU><<<dim3(24, 16), 256, 0, stream>>>(
        lnb, w1 + (long)li * I_ * E_, b1 + li * I_, nullptr, big, NT, I_, E_);
    mgemm<EPI_RES><<<dim3(6, 16), 256, 0, stream>>>(
        big, w2 + (long)li * E_ * I_, b2 + li * E_, h, h, NT, E_, I_);
  }

  ln_k<<<NT, 256, 0, stream>>>(h, lnfg, lnfb, lnb);
  mgemm<EPI_NONE><<<dim3((V_ + 127) / 128, 16), 256, 0, stream>>>(
      lnb, lmh, nullptr, nullptr, out_logits, NT, V_, E_);
  loss_k<<<1, 256, 0, stream>>>(out_rl, dep, out_loss);
}